// Round 1
// baseline (458.597 us; speedup 1.0000x reference)
//
#include <hip/hip_runtime.h>

#define B 256
#define KDIM 8
#define IDIM 1152
#define CDIM 10
#define ODIM 16
// C*O = 160, O*K = 128, C*O*K = 1280

// ---------------------------------------------------------------------------
// Kernel 1: transpose x[B][K][I] -> xt[I][K][B]; also zero routing logits.
// grid (I/32, B/32, K), block (32,8)
// ---------------------------------------------------------------------------
__global__ void k_transpose(const float* __restrict__ x, float* __restrict__ xt,
                            float* __restrict__ logits) {
  __shared__ float tile[32][33];
  const int k  = blockIdx.z;
  const int i0 = blockIdx.x * 32;
  const int b0 = blockIdx.y * 32;
  const int tx = threadIdx.x, ty = threadIdx.y;
#pragma unroll
  for (int r = 0; r < 4; ++r) {
    int b = b0 + ty + r * 8;
    tile[ty + r * 8][tx] = x[((size_t)b * KDIM + k) * IDIM + i0 + tx];
  }
  __syncthreads();
#pragma unroll
  for (int r = 0; r < 4; ++r) {
    int i = i0 + ty + r * 8;
    xt[((size_t)i * KDIM + k) * B + b0 + tx] = tile[tx][ty + r * 8];
  }
  if (blockIdx.x == 0 && blockIdx.y == 0 && blockIdx.z == 0) {
    int t = ty * 32 + tx;
    for (int idx = t; idx < IDIM * CDIM; idx += 256) logits[idx] = 0.f;
  }
}

// ---------------------------------------------------------------------------
// Kernel 2: per-block softmax over i (for its class c) + fused s-GEMM.
// s[b,c,o] = (1/Z_c) * sum_i exp(logit[i,c]-m_c) * sum_k W[i,c,o,k]*xt[i,k,b]
// grid (B/16, C) = (16,10), block 256 = (bb 0..15) x (oo 0..15)
// ---------------------------------------------------------------------------
__global__ void __launch_bounds__(256) k_s(const float* __restrict__ logits,
                                           const float* __restrict__ W,
                                           const float* __restrict__ xt,
                                           float* __restrict__ s) {
  const int c  = blockIdx.y;
  const int b0 = blockIdx.x * 16;
  const int t  = threadIdx.x;

  __shared__ float cls[IDIM];
  __shared__ float red[4];
  __shared__ float Wl[16][128];
  __shared__ float xl[16][8][16];

  // ---- softmax over i for column c (redundant per b-tile; tiny) ----
  float m = -1e30f;
  for (int i = t; i < IDIM; i += 256) {
    float v = logits[i * CDIM + c];
    cls[i] = v;
    m = fmaxf(m, v);
  }
#pragma unroll
  for (int off = 32; off; off >>= 1) m = fmaxf(m, __shfl_xor(m, off));
  if ((t & 63) == 0) red[t >> 6] = m;
  __syncthreads();
  m = fmaxf(fmaxf(red[0], red[1]), fmaxf(red[2], red[3]));
  __syncthreads();
  float psum = 0.f;
  for (int i = t; i < IDIM; i += 256) {
    float e = expf(cls[i] - m);
    cls[i] = e;
    psum += e;
  }
#pragma unroll
  for (int off = 32; off; off >>= 1) psum += __shfl_xor(psum, off);
  __syncthreads();
  if ((t & 63) == 0) red[t >> 6] = psum;
  __syncthreads();
  const float rinv = 1.f / (red[0] + red[1] + red[2] + red[3]);

  // ---- main loop over i in chunks of 16 ----
  const int bb = t & 15;
  const int oo = t >> 4;
  float acc = 0.f;
  for (int i0 = 0; i0 < IDIM; i0 += 16) {
#pragma unroll
    for (int r = 0; r < 8; ++r) {
      int idx = r * 256 + t;
      int ii = idx >> 7;
      int e  = idx & 127;
      Wl[ii][e] = W[((size_t)(i0 + ii) * CDIM + c) * 128 + e];
      int k2 = e >> 4;
      int b2 = e & 15;
      xl[ii][k2][b2] = xt[((size_t)(i0 + ii) * KDIM + k2) * B + b0 + b2];
    }
    __syncthreads();
#pragma unroll
    for (int ii = 0; ii < 16; ++ii) {
      float w = cls[i0 + ii];
      float dot = 0.f;
#pragma unroll
      for (int k = 0; k < 8; ++k) dot += Wl[ii][oo * 8 + k] * xl[ii][k][bb];
      acc += w * dot;
    }
    __syncthreads();
  }
  s[(size_t)(b0 + bb) * 160 + c * 16 + oo] = acc * rinv;
}

// ---------------------------------------------------------------------------
// Kernel 3: squash over the class dim. grid 16, block 256 -> one (b,o) each.
// ---------------------------------------------------------------------------
__global__ void k_squash(const float* __restrict__ s, float* __restrict__ out) {
  int idx = blockIdx.x * 256 + threadIdx.x;  // 0..4095 = (b,o)
  int b = idx >> 4, o = idx & 15;
  float v[CDIM];
  float ns = 0.f;
#pragma unroll
  for (int c = 0; c < CDIM; ++c) {
    float x = s[(size_t)b * 160 + c * 16 + o];
    v[c] = x;
    ns += x * x;
  }
  float scale = sqrtf(ns) + 1e-10f;
  float mag = ns / (1.f + ns);
  float f = mag / scale;
#pragma unroll
  for (int c = 0; c < CDIM; ++c) out[(size_t)b * 160 + c * 16 + o] = v[c] * f;
}

// ---------------------------------------------------------------------------
// Kernel 4: agreement + logit update.
// M_i[k,co] = sum_b xt[i,k,b]*out[b,co];  agr[i,c]=(1/B) sum_{o,k} W[i,c,o,k]*M_i[k,c*16+o]
// grid 288 (4 i's per block), block 320 = (k 0..7) x (g 0..39; co quad g*4..g*4+3)
// ---------------------------------------------------------------------------
__global__ void __launch_bounds__(320) k_agr(const float* __restrict__ W,
                                             const float* __restrict__ xt,
                                             const float* __restrict__ out,
                                             float* __restrict__ logits) {
  const int i0 = blockIdx.x * 4;
  const int t = threadIdx.x;
  const int k = t / 40;
  const int g = t % 40;

  __shared__ float xl[4][8][256];   // 32 KB
  __shared__ float Ml[4][8][160];   // 20 KB

  for (int idx = t; idx < 4 * 8 * 256; idx += 320) {
    int ii = idx >> 11;
    int rem = idx & 2047;
    int kk = rem >> 8;
    int b = rem & 255;
    xl[ii][kk][b] = xt[((size_t)(i0 + ii) * KDIM + kk) * B + b];
  }
  __syncthreads();

  float acc[4][4] = {};
  for (int b = 0; b < B; ++b) {
    float4 ov = *reinterpret_cast<const float4*>(&out[(size_t)b * 160 + g * 4]);
#pragma unroll
    for (int ii = 0; ii < 4; ++ii) {
      float xv = xl[ii][k][b];
      acc[ii][0] += xv * ov.x;
      acc[ii][1] += xv * ov.y;
      acc[ii][2] += xv * ov.z;
      acc[ii][3] += xv * ov.w;
    }
  }
#pragma unroll
  for (int ii = 0; ii < 4; ++ii) {
#pragma unroll
    for (int j = 0; j < 4; ++j) Ml[ii][k][g * 4 + j] = acc[ii][j];
  }
  __syncthreads();

  if (t < 40) {
    int ii = t / 10, c = t % 10;
    const float* Wrow = &W[((size_t)(i0 + ii) * CDIM + c) * 128];  // [o][k]
    float sum = 0.f;
#pragma unroll
    for (int o = 0; o < ODIM; ++o)
#pragma unroll
      for (int kk = 0; kk < KDIM; ++kk)
        sum += Wrow[o * 8 + kk] * Ml[ii][kk][c * 16 + o];
    int li = (i0 + ii) * CDIM + c;
    logits[li] = logits[li] + sum * (1.f / 256.f);
  }
}

// ---------------------------------------------------------------------------
extern "C" void kernel_launch(void* const* d_in, const int* in_sizes, int n_in,
                              void* d_out, int out_size, void* d_ws, size_t ws_size,
                              hipStream_t stream) {
  const float* x = (const float*)d_in[0];       // [B,K,I]
  const float* W = (const float*)d_in[1];       // [I,C,O,K]
  float* out = (float*)d_out;                   // [B,C,O,1] == [B,C,O]

  float* xt     = (float*)d_ws;                 // I*K*B = 2,359,296 floats
  float* logits = xt + (size_t)IDIM * KDIM * B; // I*C   = 11,520 floats
  float* s      = logits + IDIM * CDIM;         // B*C*O = 40,960 floats

  k_transpose<<<dim3(IDIM / 32, B / 32, KDIM), dim3(32, 8), 0, stream>>>(x, xt, logits);

  for (int it = 0; it < 3; ++it) {
    k_s<<<dim3(B / 16, CDIM), 256, 0, stream>>>(logits, W, xt, s);
    k_squash<<<16, 256, 0, stream>>>(s, out);
    if (it < 2) k_agr<<<288, 320, 0, stream>>>(W, xt, out, logits);
  }
}

// Round 2
// 190.019 us; speedup vs baseline: 2.4134x; 2.4134x over previous
//
#include <hip/hip_runtime.h>

#define B 256
#define KDIM 8
#define IDIM 1152
#define CDIM 10
#define ODIM 16
#define CO 160
#define SUB 8

// ---------------------------------------------------------------------------
// Kernel 1: transpose x[B][K][I] -> xt[I][K][B]; also zero routing logits.
// grid (I/32, B/32, K), block (32,8)
// ---------------------------------------------------------------------------
__global__ void k_transpose(const float* __restrict__ x, float* __restrict__ xt,
                            float* __restrict__ logits) {
  __shared__ float tile[32][33];
  const int k  = blockIdx.z;
  const int i0 = blockIdx.x * 32;
  const int b0 = blockIdx.y * 32;
  const int tx = threadIdx.x, ty = threadIdx.y;
#pragma unroll
  for (int r = 0; r < 4; ++r) {
    int b = b0 + ty + r * 8;
    tile[ty + r * 8][tx] = x[((size_t)b * KDIM + k) * IDIM + i0 + tx];
  }
  __syncthreads();
#pragma unroll
  for (int r = 0; r < 4; ++r) {
    int i = i0 + ty + r * 8;
    xt[((size_t)i * KDIM + k) * B + b0 + tx] = tile[tx][ty + r * 8];
  }
  if (blockIdx.x == 0 && blockIdx.y == 0 && blockIdx.z == 0) {
    int t = ty * 32 + tx;
    for (int idx = t; idx < IDIM * CDIM; idx += 256) logits[idx] = 0.f;
  }
}

// ---------------------------------------------------------------------------
// Kernel 2: per-class softmax over i.  qT[c][i] = softmax_i(logits[i][c])
// grid (10), block 256
// ---------------------------------------------------------------------------
__global__ void __launch_bounds__(256) k_q(const float* __restrict__ logits,
                                           float* __restrict__ qT) {
  const int c = blockIdx.x;
  const int t = threadIdx.x;
  __shared__ float cls[IDIM];
  __shared__ float red[4];

  float m = -1e30f;
  for (int i = t; i < IDIM; i += 256) {
    float v = logits[i * CDIM + c];
    cls[i] = v;
    m = fmaxf(m, v);
  }
#pragma unroll
  for (int off = 32; off; off >>= 1) m = fmaxf(m, __shfl_xor(m, off));
  if ((t & 63) == 0) red[t >> 6] = m;
  __syncthreads();
  m = fmaxf(fmaxf(red[0], red[1]), fmaxf(red[2], red[3]));
  __syncthreads();
  float ps = 0.f;
  for (int i = t; i < IDIM; i += 256) {
    float e = expf(cls[i] - m);
    cls[i] = e;
    ps += e;
  }
#pragma unroll
  for (int off = 32; off; off >>= 1) ps += __shfl_xor(ps, off);
  if ((t & 63) == 0) red[t >> 6] = ps;
  __syncthreads();
  const float rinv = 1.f / (red[0] + red[1] + red[2] + red[3]);
  for (int i = t; i < IDIM; i += 256) qT[c * IDIM + i] = cls[i] * rinv;
}

// ---------------------------------------------------------------------------
// Kernel 3: split-K s-GEMM.
// s_part[is][b][c*16+o] = sum_{i in chunk} qT[c][i] * sum_k W[i,c,o,k]*xt[i,k,b]
// grid (nP, 4 b-tiles of 64, 10 c), block 256 (4 waves).
// Wave w handles sub-chunk rows ii = 2w, 2w+1.  Per-thread tile: 4b x 4o.
// lane l: lb = l&15 -> b = b0 + lb*4 + j,  lq = l>>4 -> o = lq*4 + m
// ---------------------------------------------------------------------------
__global__ void __launch_bounds__(256) k_s(const float* __restrict__ qT,
                                           const float* __restrict__ W,
                                           const float* __restrict__ xt,
                                           float* __restrict__ s_part, int ich) {
  const int is = blockIdx.x;
  const int b0 = blockIdx.y * 64;
  const int c  = blockIdx.z;
  const int i0 = is * ich;
  const int t = threadIdx.x;
  const int w = t >> 6;
  const int l = t & 63;
  const int lb = l & 15;
  const int lq = l >> 4;

  __shared__ __align__(16) float xl[SUB * 8 * 64];  // [(ii*8+k)][bb]  16 KB
  __shared__ __align__(16) float wl[SUB * 128];     // [ii][o*8+k]      4 KB

  float acc[4][4];
#pragma unroll
  for (int m = 0; m < 4; ++m)
#pragma unroll
    for (int j = 0; j < 4; ++j) acc[m][j] = 0.f;

  for (int s0 = 0; s0 < ich; s0 += SUB) {
    // ---- stage Wq (1024 floats): thread t loads float4 at e = (t*4)&127 ----
    {
      int idx = t * 4;
      int ii = idx >> 7;
      int e = idx & 127;
      float qv = qT[c * IDIM + i0 + s0 + ii];
      float4 wv = *reinterpret_cast<const float4*>(
          &W[((size_t)(i0 + s0 + ii) * CDIM + c) * 128 + e]);
      wv.x *= qv; wv.y *= qv; wv.z *= qv; wv.w *= qv;
      *reinterpret_cast<float4*>(&wl[idx]) = wv;
    }
    // ---- stage x (4096 floats) ----
#pragma unroll
    for (int r = 0; r < 4; ++r) {
      int idx = r * 1024 + t * 4;
      int row = idx >> 6;        // ii*8 + k
      int bb = idx & 63;
      int ii = row >> 3, k = row & 7;
      *reinterpret_cast<float4*>(&xl[idx]) = *reinterpret_cast<const float4*>(
          &xt[((size_t)(i0 + s0 + ii) * KDIM + k) * B + b0 + bb]);
    }
    __syncthreads();

#pragma unroll
    for (int u = 0; u < 2; ++u) {
      const int ii = w * 2 + u;
      float4 xv[8];
#pragma unroll
      for (int k = 0; k < 8; ++k)
        xv[k] = *reinterpret_cast<const float4*>(&xl[(ii * 8 + k) * 64 + lb * 4]);
#pragma unroll
      for (int m = 0; m < 4; ++m) {
        const float* wr = &wl[ii * 128 + (lq * 4 + m) * 8];
        float4 wa = *reinterpret_cast<const float4*>(&wr[0]);
        float4 wb = *reinterpret_cast<const float4*>(&wr[4]);
        acc[m][0] += xv[0].x*wa.x + xv[1].x*wa.y + xv[2].x*wa.z + xv[3].x*wa.w
                   + xv[4].x*wb.x + xv[5].x*wb.y + xv[6].x*wb.z + xv[7].x*wb.w;
        acc[m][1] += xv[0].y*wa.x + xv[1].y*wa.y + xv[2].y*wa.z + xv[3].y*wa.w
                   + xv[4].y*wb.x + xv[5].y*wb.y + xv[6].y*wb.z + xv[7].y*wb.w;
        acc[m][2] += xv[0].z*wa.x + xv[1].z*wa.y + xv[2].z*wa.z + xv[3].z*wa.w
                   + xv[4].z*wb.x + xv[5].z*wb.y + xv[6].z*wb.z + xv[7].z*wb.w;
        acc[m][3] += xv[0].w*wa.x + xv[1].w*wa.y + xv[2].w*wa.z + xv[3].w*wa.w
                   + xv[4].w*wb.x + xv[5].w*wb.y + xv[6].w*wb.z + xv[7].w*wb.w;
      }
    }
    __syncthreads();
  }

  // ---- cross-wave reduce (waves accumulated different i's) ----
  if (w) {
    float* dst = &xl[(w - 1) * 1024 + l * 16];
#pragma unroll
    for (int m = 0; m < 4; ++m) {
      float4 v = make_float4(acc[m][0], acc[m][1], acc[m][2], acc[m][3]);
      *reinterpret_cast<float4*>(&dst[m * 4]) = v;
    }
  }
  __syncthreads();
  if (w == 0) {
#pragma unroll
    for (int r = 0; r < 3; ++r) {
      const float* src = &xl[r * 1024 + l * 16];
#pragma unroll
      for (int m = 0; m < 4; ++m) {
        float4 v = *reinterpret_cast<const float4*>(&src[m * 4]);
        acc[m][0] += v.x; acc[m][1] += v.y; acc[m][2] += v.z; acc[m][3] += v.w;
      }
    }
#pragma unroll
    for (int j = 0; j < 4; ++j) {
      float4 o4 = make_float4(acc[0][j], acc[1][j], acc[2][j], acc[3][j]);
      *reinterpret_cast<float4*>(
          &s_part[((size_t)is * B + b0 + lb * 4 + j) * CO + c * 16 + lq * 4]) = o4;
    }
  }
}

// ---------------------------------------------------------------------------
// Kernel 4: reduce partials + squash over classes. grid 16, block 256.
// ---------------------------------------------------------------------------
__global__ void __launch_bounds__(256) k_squash(const float* __restrict__ s_part,
                                                float* __restrict__ out, int nP) {
  int idx = blockIdx.x * 256 + threadIdx.x;  // (b,o)
  int b = idx >> 4, o = idx & 15;
  float v[CDIM];
#pragma unroll
  for (int c = 0; c < CDIM; ++c) v[c] = 0.f;
  for (int p = 0; p < nP; ++p) {
    const float* row = &s_part[((size_t)p * B + b) * CO + o];
#pragma unroll
    for (int c = 0; c < CDIM; ++c) v[c] += row[c * 16];
  }
  float ns = 0.f;
#pragma unroll
  for (int c = 0; c < CDIM; ++c) ns += v[c] * v[c];
  float f = (ns / (1.f + ns)) / (sqrtf(ns) + 1e-10f);
#pragma unroll
  for (int c = 0; c < CDIM; ++c) out[(size_t)b * CO + c * 16 + o] = v[c] * f;
}

// ---------------------------------------------------------------------------
// Kernel 5: agreement + logit update (4 i per block).
// ---------------------------------------------------------------------------
__global__ void __launch_bounds__(320) k_agr(const float* __restrict__ W,
                                             const float* __restrict__ xt,
                                             const float* __restrict__ out,
                                             float* __restrict__ logits) {
  const int i0 = blockIdx.x * 4;
  const int t = threadIdx.x;
  const int k = t / 40;
  const int g = t % 40;

  __shared__ float xl[4][8][256];   // 32 KB
  __shared__ float Ml[4][8][160];   // 20 KB

  for (int idx = t; idx < 4 * 8 * 256; idx += 320) {
    int ii = idx >> 11;
    int rem = idx & 2047;
    int kk = rem >> 8;
    int b = rem & 255;
    xl[ii][kk][b] = xt[((size_t)(i0 + ii) * KDIM + kk) * B + b];
  }
  __syncthreads();

  float acc[4][4] = {};
  for (int b = 0; b < B; ++b) {
    float4 ov = *reinterpret_cast<const float4*>(&out[(size_t)b * CO + g * 4]);
#pragma unroll
    for (int ii = 0; ii < 4; ++ii) {
      float xv = xl[ii][k][b];
      acc[ii][0] += xv * ov.x;
      acc[ii][1] += xv * ov.y;
      acc[ii][2] += xv * ov.z;
      acc[ii][3] += xv * ov.w;
    }
  }
#pragma unroll
  for (int ii = 0; ii < 4; ++ii) {
#pragma unroll
    for (int j = 0; j < 4; ++j) Ml[ii][k][g * 4 + j] = acc[ii][j];
  }
  __syncthreads();

  if (t < 40) {
    int ii = t / 10, c = t % 10;
    const float* Wrow = &W[((size_t)(i0 + ii) * CDIM + c) * 128];  // [o][k]
    float sum = 0.f;
#pragma unroll
    for (int o = 0; o < ODIM; ++o)
#pragma unroll
      for (int kk = 0; kk < KDIM; ++kk)
        sum += Wrow[o * 8 + kk] * Ml[ii][kk][c * 16 + o];
    int li = (i0 + ii) * CDIM + c;
    logits[li] = logits[li] + sum * (1.f / 256.f);
  }
}

// ---------------------------------------------------------------------------
extern "C" void kernel_launch(void* const* d_in, const int* in_sizes, int n_in,
                              void* d_out, int out_size, void* d_ws, size_t ws_size,
                              hipStream_t stream) {
  const float* x = (const float*)d_in[0];       // [B,K,I]
  const float* W = (const float*)d_in[1];       // [I,C,O,K]
  float* out = (float*)d_out;                   // [B,C,O,1] == [B,C,O]

  float* xt     = (float*)d_ws;                     // I*K*B floats
  float* logits = xt + (size_t)IDIM * KDIM * B;     // I*C
  float* qT     = logits + IDIM * CDIM;             // C*I
  float* s_part = qT + IDIM * CDIM;                 // nP*B*CO

  // pick i-split count based on available workspace
  const size_t base = (size_t)IDIM * KDIM * B + 2 * IDIM * CDIM;
  int nP = 24;
  if ((base + (size_t)nP * B * CO) * 4 > ws_size) nP = 8;
  if ((base + (size_t)nP * B * CO) * 4 > ws_size) nP = 2;
  const int ich = IDIM / nP;

  k_transpose<<<dim3(IDIM / 32, B / 32, KDIM), dim3(32, 8), 0, stream>>>(x, xt, logits);

  for (int it = 0; it < 3; ++it) {
    k_q<<<CDIM, 256, 0, stream>>>(logits, qT);
    k_s<<<dim3(nP, 4, CDIM), 256, 0, stream>>>(qT, W, xt, s_part, ich);
    k_squash<<<16, 256, 0, stream>>>(s_part, out, nP);
    if (it < 2) k_agr<<<288, 320, 0, stream>>>(W, xt, out, logits);
  }
}

// Round 3
// 148.944 us; speedup vs baseline: 3.0790x; 1.2758x over previous
//
#include <hip/hip_runtime.h>

#define B 256
#define KDIM 8
#define IDIM 1152
#define CDIM 10
#define ODIM 16
#define CO 160
#define SUB 8
#define IT 8          // i's per k_agr block
#define BSPL 4        // b splits in k_agr
#define BCH (B / BSPL)

// ---------------------------------------------------------------------------
// Kernel 1: transpose x[B][K][I] -> xt[I][K][B]; also zero routing logits.
// ---------------------------------------------------------------------------
__global__ void k_transpose(const float* __restrict__ x, float* __restrict__ xt,
                            float* __restrict__ logits) {
  __shared__ float tile[32][33];
  const int k  = blockIdx.z;
  const int i0 = blockIdx.x * 32;
  const int b0 = blockIdx.y * 32;
  const int tx = threadIdx.x, ty = threadIdx.y;
#pragma unroll
  for (int r = 0; r < 4; ++r) {
    int b = b0 + ty + r * 8;
    tile[ty + r * 8][tx] = x[((size_t)b * KDIM + k) * IDIM + i0 + tx];
  }
  __syncthreads();
#pragma unroll
  for (int r = 0; r < 4; ++r) {
    int i = i0 + ty + r * 8;
    xt[((size_t)i * KDIM + k) * B + b0 + tx] = tile[tx][ty + r * 8];
  }
  if (blockIdx.x == 0 && blockIdx.y == 0 && blockIdx.z == 0) {
    int t = ty * 32 + tx;
    for (int idx = t; idx < IDIM * CDIM; idx += 256) logits[idx] = 0.f;
  }
}

// ---------------------------------------------------------------------------
// Kernel 2: per-class softmax over i.  qT[c][i] = softmax_i(logits[i][c])
// ---------------------------------------------------------------------------
__global__ void __launch_bounds__(256) k_q(const float* __restrict__ logits,
                                           float* __restrict__ qT) {
  const int c = blockIdx.x;
  const int t = threadIdx.x;
  __shared__ float cls[IDIM];
  __shared__ float red[4];

  float m = -1e30f;
  for (int i = t; i < IDIM; i += 256) {
    float v = logits[i * CDIM + c];
    cls[i] = v;
    m = fmaxf(m, v);
  }
#pragma unroll
  for (int off = 32; off; off >>= 1) m = fmaxf(m, __shfl_xor(m, off));
  if ((t & 63) == 0) red[t >> 6] = m;
  __syncthreads();
  m = fmaxf(fmaxf(red[0], red[1]), fmaxf(red[2], red[3]));
  __syncthreads();
  float ps = 0.f;
  for (int i = t; i < IDIM; i += 256) {
    float e = expf(cls[i] - m);
    cls[i] = e;
    ps += e;
  }
#pragma unroll
  for (int off = 32; off; off >>= 1) ps += __shfl_xor(ps, off);
  if ((t & 63) == 0) red[t >> 6] = ps;
  __syncthreads();
  const float rinv = 1.f / (red[0] + red[1] + red[2] + red[3]);
  for (int i = t; i < IDIM; i += 256) qT[c * IDIM + i] = cls[i] * rinv;
}

// ---------------------------------------------------------------------------
// Kernel 3: split-K s-GEMM (unchanged from round 2).
// ---------------------------------------------------------------------------
__global__ void __launch_bounds__(256) k_s(const float* __restrict__ qT,
                                           const float* __restrict__ W,
                                           const float* __restrict__ xt,
                                           float* __restrict__ s_part, int ich) {
  const int is = blockIdx.x;
  const int b0 = blockIdx.y * 64;
  const int c  = blockIdx.z;
  const int i0 = is * ich;
  const int t = threadIdx.x;
  const int w = t >> 6;
  const int l = t & 63;
  const int lb = l & 15;
  const int lq = l >> 4;

  __shared__ __align__(16) float xl[SUB * 8 * 64];
  __shared__ __align__(16) float wl[SUB * 128];

  float acc[4][4];
#pragma unroll
  for (int m = 0; m < 4; ++m)
#pragma unroll
    for (int j = 0; j < 4; ++j) acc[m][j] = 0.f;

  for (int s0 = 0; s0 < ich; s0 += SUB) {
    {
      int idx = t * 4;
      int ii = idx >> 7;
      int e = idx & 127;
      float qv = qT[c * IDIM + i0 + s0 + ii];
      float4 wv = *reinterpret_cast<const float4*>(
          &W[((size_t)(i0 + s0 + ii) * CDIM + c) * 128 + e]);
      wv.x *= qv; wv.y *= qv; wv.z *= qv; wv.w *= qv;
      *reinterpret_cast<float4*>(&wl[idx]) = wv;
    }
#pragma unroll
    for (int r = 0; r < 4; ++r) {
      int idx = r * 1024 + t * 4;
      int row = idx >> 6;
      int bb = idx & 63;
      int ii = row >> 3, k = row & 7;
      *reinterpret_cast<float4*>(&xl[idx]) = *reinterpret_cast<const float4*>(
          &xt[((size_t)(i0 + s0 + ii) * KDIM + k) * B + b0 + bb]);
    }
    __syncthreads();

#pragma unroll
    for (int u = 0; u < 2; ++u) {
      const int ii = w * 2 + u;
      float4 xv[8];
#pragma unroll
      for (int k = 0; k < 8; ++k)
        xv[k] = *reinterpret_cast<const float4*>(&xl[(ii * 8 + k) * 64 + lb * 4]);
#pragma unroll
      for (int m = 0; m < 4; ++m) {
        const float* wr = &wl[ii * 128 + (lq * 4 + m) * 8];
        float4 wa = *reinterpret_cast<const float4*>(&wr[0]);
        float4 wb = *reinterpret_cast<const float4*>(&wr[4]);
        acc[m][0] += xv[0].x*wa.x + xv[1].x*wa.y + xv[2].x*wa.z + xv[3].x*wa.w
                   + xv[4].x*wb.x + xv[5].x*wb.y + xv[6].x*wb.z + xv[7].x*wb.w;
        acc[m][1] += xv[0].y*wa.x + xv[1].y*wa.y + xv[2].y*wa.z + xv[3].y*wa.w
                   + xv[4].y*wb.x + xv[5].y*wb.y + xv[6].y*wb.z + xv[7].y*wb.w;
        acc[m][2] += xv[0].z*wa.x + xv[1].z*wa.y + xv[2].z*wa.z + xv[3].z*wa.w
                   + xv[4].z*wb.x + xv[5].z*wb.y + xv[6].z*wb.z + xv[7].z*wb.w;
        acc[m][3] += xv[0].w*wa.x + xv[1].w*wa.y + xv[2].w*wa.z + xv[3].w*wa.w
                   + xv[4].w*wb.x + xv[5].w*wb.y + xv[6].w*wb.z + xv[7].w*wb.w;
      }
    }
    __syncthreads();
  }

  if (w) {
    float* dst = &xl[(w - 1) * 1024 + l * 16];
#pragma unroll
    for (int m = 0; m < 4; ++m) {
      float4 v = make_float4(acc[m][0], acc[m][1], acc[m][2], acc[m][3]);
      *reinterpret_cast<float4*>(&dst[m * 4]) = v;
    }
  }
  __syncthreads();
  if (w == 0) {
#pragma unroll
    for (int r = 0; r < 3; ++r) {
      const float* src = &xl[r * 1024 + l * 16];
#pragma unroll
      for (int m = 0; m < 4; ++m) {
        float4 v = *reinterpret_cast<const float4*>(&src[m * 4]);
        acc[m][0] += v.x; acc[m][1] += v.y; acc[m][2] += v.z; acc[m][3] += v.w;
      }
    }
#pragma unroll
    for (int j = 0; j < 4; ++j) {
      float4 o4 = make_float4(acc[0][j], acc[1][j], acc[2][j], acc[3][j]);
      *reinterpret_cast<float4*>(
          &s_part[((size_t)is * B + b0 + lb * 4 + j) * CO + c * 16 + lq * 4]) = o4;
    }
  }
}

// ---------------------------------------------------------------------------
// Kernel 4: reduce partials + squash over classes (unchanged).
// ---------------------------------------------------------------------------
__global__ void __launch_bounds__(256) k_squash(const float* __restrict__ s_part,
                                                float* __restrict__ out, int nP) {
  int idx = blockIdx.x * 256 + threadIdx.x;
  int b = idx >> 4, o = idx & 15;
  float v[CDIM];
#pragma unroll
  for (int c = 0; c < CDIM; ++c) v[c] = 0.f;
  for (int p = 0; p < nP; ++p) {
    const float* row = &s_part[((size_t)p * B + b) * CO + o];
#pragma unroll
    for (int c = 0; c < CDIM; ++c) v[c] += row[c * 16];
  }
  float ns = 0.f;
#pragma unroll
  for (int c = 0; c < CDIM; ++c) ns += v[c] * v[c];
  float f = (ns / (1.f + ns)) / (sqrtf(ns) + 1e-10f);
#pragma unroll
  for (int c = 0; c < CDIM; ++c) out[(size_t)b * CO + c * 16 + o] = v[c] * f;
}

// ---------------------------------------------------------------------------
// Kernel 5 (REWRITTEN): agreement via y-GEMM + W-contraction + atomic logits.
// y[ik][co] = sum_b xt[ik][b]*out[b][co]  (partial over this block's 64 b's)
// agr_part[ii][c] = sum_{k,o} W[i,c,o,k] * y[ii*8+k][c*16+o]
// grid (144, 4), block 256: rg = t>>5 (8 rows each), cg = t&31 (5 cols each)
// ---------------------------------------------------------------------------
__global__ void __launch_bounds__(256) k_agr(const float* __restrict__ W,
                                             const float* __restrict__ xt,
                                             const float* __restrict__ out,
                                             float* __restrict__ logits) {
  const int i0 = blockIdx.x * IT;
  const int b0 = blockIdx.y * BCH;
  const int t = threadIdx.x;
  const int rg = t >> 5;
  const int cg = t & 31;

  __shared__ __align__(16) float xtl[BCH][68];     // [b][row=ik], pad->conflict-free f4 reads
  __shared__ __align__(16) float otile[BCH][161];  // [b][co] stride 161 (odd: lane banks distinct)

  // stage xt rows (64 rows x 64 b), transposing into [b][row]
#pragma unroll
  for (int v = 0; v < 4; ++v) {
    int idx = v * 256 + t;        // (row, bq)
    int r = idx >> 4;             // 0..63 = ii*8+k
    int bq = idx & 15;
    int ii = r >> 3, k = r & 7;
    float4 xv = *reinterpret_cast<const float4*>(
        &xt[((size_t)(i0 + ii) * KDIM + k) * B + b0 + bq * 4]);
    xtl[bq * 4 + 0][r] = xv.x;
    xtl[bq * 4 + 1][r] = xv.y;
    xtl[bq * 4 + 2][r] = xv.z;
    xtl[bq * 4 + 3][r] = xv.w;
  }
  // stage out tile [64][160]
#pragma unroll
  for (int v = 0; v < 10; ++v) {
    int idx = (v * 256 + t) * 4;
    int bb = idx / 160;
    int e = idx % 160;
    float4 ov = *reinterpret_cast<const float4*>(&out[(size_t)(b0 + bb) * CO + e]);
    otile[bb][e + 0] = ov.x;
    otile[bb][e + 1] = ov.y;
    otile[bb][e + 2] = ov.z;
    otile[bb][e + 3] = ov.w;
  }
  __syncthreads();

  float acc[8][5];
#pragma unroll
  for (int r = 0; r < 8; ++r)
#pragma unroll
    for (int j = 0; j < 5; ++j) acc[r][j] = 0.f;

  for (int b = 0; b < BCH; ++b) {
    float4 xa = *reinterpret_cast<const float4*>(&xtl[b][rg * 8]);
    float4 xb = *reinterpret_cast<const float4*>(&xtl[b][rg * 8 + 4]);
    float ov[5];
#pragma unroll
    for (int j = 0; j < 5; ++j) ov[j] = otile[b][cg * 5 + j];
    float xr[8] = {xa.x, xa.y, xa.z, xa.w, xb.x, xb.y, xb.z, xb.w};
#pragma unroll
    for (int r = 0; r < 8; ++r)
#pragma unroll
      for (int j = 0; j < 5; ++j) acc[r][j] += xr[r] * ov[j];
  }

  // write y back into otile as yl[row][co] (all otile reads are done)
  __syncthreads();
#pragma unroll
  for (int r = 0; r < 8; ++r)
#pragma unroll
    for (int j = 0; j < 5; ++j) otile[rg * 8 + r][cg * 5 + j] = acc[r][j];
  __syncthreads();

  // contract with W: 160 threads = (ii 0..7) x (c 0..9) x (oh 0..1)
  if (t < 160) {
    int ii = t / 20, rem = t % 20, c = rem >> 1, oh = rem & 1;
    const float* Wp = &W[((size_t)(i0 + ii) * CDIM + c) * 128 + oh * 64];  // [o][k]
    float sum = 0.f;
#pragma unroll
    for (int o = 0; o < 8; ++o) {
      float4 w0 = *reinterpret_cast<const float4*>(&Wp[o * 8]);
      float4 w1 = *reinterpret_cast<const float4*>(&Wp[o * 8 + 4]);
      int co = c * 16 + oh * 8 + o;
      sum += w0.x * otile[ii * 8 + 0][co] + w0.y * otile[ii * 8 + 1][co]
           + w0.z * otile[ii * 8 + 2][co] + w0.w * otile[ii * 8 + 3][co]
           + w1.x * otile[ii * 8 + 4][co] + w1.y * otile[ii * 8 + 5][co]
           + w1.z * otile[ii * 8 + 6][co] + w1.w * otile[ii * 8 + 7][co];
    }
    sum += __shfl_xor(sum, 1);
    if (oh == 0) atomicAdd(&logits[(i0 + ii) * CDIM + c], sum * (1.f / B));
  }
}

// ---------------------------------------------------------------------------
extern "C" void kernel_launch(void* const* d_in, const int* in_sizes, int n_in,
                              void* d_out, int out_size, void* d_ws, size_t ws_size,
                              hipStream_t stream) {
  const float* x = (const float*)d_in[0];
  const float* W = (const float*)d_in[1];
  float* out = (float*)d_out;

  float* xt     = (float*)d_ws;
  float* logits = xt + (size_t)IDIM * KDIM * B;
  float* qT     = logits + IDIM * CDIM;
  float* s_part = qT + IDIM * CDIM;

  const size_t base = (size_t)IDIM * KDIM * B + 2 * IDIM * CDIM;
  int nP = 24;
  if ((base + (size_t)nP * B * CO) * 4 > ws_size) nP = 8;
  if ((base + (size_t)nP * B * CO) * 4 > ws_size) nP = 2;
  const int ich = IDIM / nP;

  k_transpose<<<dim3(IDIM / 32, B / 32, KDIM), dim3(32, 8), 0, stream>>>(x, xt, logits);

  for (int it = 0; it < 3; ++it) {
    k_q<<<CDIM, 256, 0, stream>>>(logits, qT);
    k_s<<<dim3(nP, 4, CDIM), 256, 0, stream>>>(qT, W, xt, s_part, ich);
    k_squash<<<16, 256, 0, stream>>>(s_part, out, nP);
    if (it < 2) k_agr<<<dim3(IDIM / IT, BSPL), 256, 0, stream>>>(W, xt, out, logits);
  }
}

// Round 4
// 120.440 us; speedup vs baseline: 3.8077x; 1.2367x over previous
//
#include <hip/hip_runtime.h>

#define B 256
#define KDIM 8
#define IDIM 1152
#define CDIM 10
#define ODIM 16
#define CO 160
#define IK 9216        // IDIM*KDIM
#define NPART 8        // s_part splits
#define IT 8           // i's per k_agr block
#define BSPL 4         // b splits in k_agr
#define BCH (B / BSPL)

typedef __bf16 bf16x8 __attribute__((ext_vector_type(8)));
typedef unsigned short ushort8 __attribute__((ext_vector_type(8)));
typedef float f32x4 __attribute__((ext_vector_type(4)));

__device__ __forceinline__ unsigned short f2bf(float f) {
  unsigned u = __float_as_uint(f);
  unsigned r = u + 0x7fff + ((u >> 16) & 1);   // RNE
  return (unsigned short)(r >> 16);
}

union U8B8 { ushort8 u; bf16x8 h; };

// ---------------------------------------------------------------------------
// Kernel 1: transpose x[B][K][I] -> xt[I][K][B] (f32, for k_agr); zero logits.
// ---------------------------------------------------------------------------
__global__ void k_transpose(const float* __restrict__ x, float* __restrict__ xt,
                            float* __restrict__ logits) {
  __shared__ float tile[32][33];
  const int k  = blockIdx.z;
  const int i0 = blockIdx.x * 32;
  const int b0 = blockIdx.y * 32;
  const int tx = threadIdx.x, ty = threadIdx.y;
#pragma unroll
  for (int r = 0; r < 4; ++r) {
    int b = b0 + ty + r * 8;
    tile[ty + r * 8][tx] = x[((size_t)b * KDIM + k) * IDIM + i0 + tx];
  }
  __syncthreads();
#pragma unroll
  for (int r = 0; r < 4; ++r) {
    int i = i0 + ty + r * 8;
    xt[((size_t)i * KDIM + k) * B + b0 + tx] = tile[tx][ty + r * 8];
  }
  if (blockIdx.x == 0 && blockIdx.y == 0 && blockIdx.z == 0) {
    int t = ty * 32 + tx;
    for (int idx = t; idx < IDIM * CDIM; idx += 256) logits[idx] = 0.f;
  }
}

// ---------------------------------------------------------------------------
// Kernel 1b: pack xtbT[b][i*8+k] = bf16(x[b][k][i]).  grid (9, 256), block 128
// ---------------------------------------------------------------------------
__global__ void __launch_bounds__(128) k_xtb(const float* __restrict__ x,
                                             unsigned short* __restrict__ xtbT) {
  const int i = blockIdx.x * 128 + threadIdx.x;
  const int b = blockIdx.y;
  ushort8 v;
#pragma unroll
  for (int k = 0; k < 8; ++k)
    v[k] = f2bf(x[((size_t)b * KDIM + k) * IDIM + i]);
  *reinterpret_cast<ushort8*>(&xtbT[(size_t)b * IK + i * 8]) = v;
}

// ---------------------------------------------------------------------------
// Kernel 1c: pack Wrb[c*16+o][i*8+k] = bf16(W[i][c][o][k]).  grid (9,160), blk 128
// ---------------------------------------------------------------------------
__global__ void __launch_bounds__(128) k_wr(const float* __restrict__ W,
                                            unsigned short* __restrict__ Wrb) {
  const int i = blockIdx.x * 128 + threadIdx.x;
  const int row = blockIdx.y;                 // c*16+o
  const int c = row >> 4, o = row & 15;
  const float* src = &W[(((size_t)i * CDIM + c) * ODIM + o) * KDIM];
  ushort8 v;
#pragma unroll
  for (int k = 0; k < 8; ++k) v[k] = f2bf(src[k]);
  *reinterpret_cast<ushort8*>(&Wrb[(size_t)row * IK + i * 8]) = v;
}

// ---------------------------------------------------------------------------
// Kernel 2: per-class softmax over i.  qT[c][i] = softmax_i(logits[i][c])
// ---------------------------------------------------------------------------
__global__ void __launch_bounds__(256) k_q(const float* __restrict__ logits,
                                           float* __restrict__ qT) {
  const int c = blockIdx.x;
  const int t = threadIdx.x;
  __shared__ float cls[IDIM];
  __shared__ float red[4];

  float m = -1e30f;
  for (int i = t; i < IDIM; i += 256) {
    float v = logits[i * CDIM + c];
    cls[i] = v;
    m = fmaxf(m, v);
  }
#pragma unroll
  for (int off = 32; off; off >>= 1) m = fmaxf(m, __shfl_xor(m, off));
  if ((t & 63) == 0) red[t >> 6] = m;
  __syncthreads();
  m = fmaxf(fmaxf(red[0], red[1]), fmaxf(red[2], red[3]));
  __syncthreads();
  float ps = 0.f;
  for (int i = t; i < IDIM; i += 256) {
    float e = expf(cls[i] - m);
    cls[i] = e;
    ps += e;
  }
#pragma unroll
  for (int off = 32; off; off >>= 1) ps += __shfl_xor(ps, off);
  if ((t & 63) == 0) red[t >> 6] = ps;
  __syncthreads();
  const float rinv = 1.f / (red[0] + red[1] + red[2] + red[3]);
  for (int i = t; i < IDIM; i += 256) qT[c * IDIM + i] = cls[i] * rinv;
}

// ---------------------------------------------------------------------------
// Kernel 3 (MFMA): s[o,b] = sum_ik (q[c,i]*Wrb[c*16+o][ik]) * xtbT[b][ik]
// grid (10 c, 4 bt4, 8 g), block 256 = 4 waves; wave split s = g*4+w covers
// 9 K-chunks of 32. Per wave: A-frag (q-scaled) + 4 B-frags + 4 MFMA / chunk.
// Fragment layouts (16x16x32): A lane l elem e -> [m=l&15][k=8*(l>>4)+e];
// B -> [k=8*(l>>4)+e][n=l&15]; D lane l reg j -> [m=(l>>4)*4+j][n=l&15].
// ---------------------------------------------------------------------------
__global__ void __launch_bounds__(256) k_s(const float* __restrict__ qT,
                                           const unsigned short* __restrict__ Wrb,
                                           const unsigned short* __restrict__ xtbT,
                                           float* __restrict__ s_part) {
  const int c = blockIdx.x, bt4 = blockIdx.y, g = blockIdx.z;
  const int t = threadIdx.x, w = t >> 6, l = t & 63;
  const int lr = l & 15, lq = l >> 4;
  const int s = g * 4 + w;

  __shared__ float red[3 * 1088];   // padded: 17 floats per lane

  f32x4 acc[4];
#pragma unroll
  for (int j = 0; j < 4; ++j) acc[j] = (f32x4){0.f, 0.f, 0.f, 0.f};

  const unsigned short* Ap = &Wrb[((size_t)c * 16 + lr) * IK + lq * 8];
  const unsigned short* Bp0 = &xtbT[((size_t)(bt4 * 64 + 0 * 16 + lr)) * IK + lq * 8];
  const unsigned short* Bp1 = &xtbT[((size_t)(bt4 * 64 + 1 * 16 + lr)) * IK + lq * 8];
  const unsigned short* Bp2 = &xtbT[((size_t)(bt4 * 64 + 2 * 16 + lr)) * IK + lq * 8];
  const unsigned short* Bp3 = &xtbT[((size_t)(bt4 * 64 + 3 * 16 + lr)) * IK + lq * 8];
  const float* qp = &qT[c * IDIM + lq];

  for (int t9 = 0; t9 < 9; ++t9) {
    const int kc = s * 9 + t9;
    const int off = kc * 32;
    ushort8 av = *reinterpret_cast<const ushort8*>(Ap + off);
    float qv = qp[kc * 4];
    U8B8 b0; b0.u = *reinterpret_cast<const ushort8*>(Bp0 + off);
    U8B8 b1; b1.u = *reinterpret_cast<const ushort8*>(Bp1 + off);
    U8B8 b2; b2.u = *reinterpret_cast<const ushort8*>(Bp2 + off);
    U8B8 b3; b3.u = *reinterpret_cast<const ushort8*>(Bp3 + off);
    U8B8 a;
#pragma unroll
    for (int e = 0; e < 8; ++e) {
      float f = __uint_as_float((unsigned)av[e] << 16) * qv;
      a.u[e] = f2bf(f);
    }
    acc[0] = __builtin_amdgcn_mfma_f32_16x16x32_bf16(a.h, b0.h, acc[0], 0, 0, 0);
    acc[1] = __builtin_amdgcn_mfma_f32_16x16x32_bf16(a.h, b1.h, acc[1], 0, 0, 0);
    acc[2] = __builtin_amdgcn_mfma_f32_16x16x32_bf16(a.h, b2.h, acc[2], 0, 0, 0);
    acc[3] = __builtin_amdgcn_mfma_f32_16x16x32_bf16(a.h, b3.h, acc[3], 0, 0, 0);
  }

  // cross-wave reduce (4 splits per block) then single store by wave 0
  if (w) {
#pragma unroll
    for (int j = 0; j < 4; ++j)
#pragma unroll
      for (int j2 = 0; j2 < 4; ++j2)
        red[(w - 1) * 1088 + l * 17 + j * 4 + j2] = acc[j][j2];
  }
  __syncthreads();
  if (w == 0) {
#pragma unroll
    for (int r = 0; r < 3; ++r)
#pragma unroll
      for (int j = 0; j < 4; ++j)
#pragma unroll
        for (int j2 = 0; j2 < 4; ++j2)
          acc[j][j2] += red[r * 1088 + l * 17 + j * 4 + j2];
    // D: b = bt4*64 + j*16 + lr (col), o = lq*4 + j2 (row)
#pragma unroll
    for (int j = 0; j < 4; ++j)
#pragma unroll
      for (int j2 = 0; j2 < 4; ++j2)
        s_part[((size_t)g * B + bt4 * 64 + j * 16 + lr) * CO + c * 16 + lq * 4 + j2] =
            acc[j][j2];
  }
}

// ---------------------------------------------------------------------------
// Kernel 4: reduce partials + squash over classes.
// ---------------------------------------------------------------------------
__global__ void __launch_bounds__(256) k_squash(const float* __restrict__ s_part,
                                                float* __restrict__ out) {
  int idx = blockIdx.x * 256 + threadIdx.x;
  int b = idx >> 4, o = idx & 15;
  float v[CDIM];
#pragma unroll
  for (int c = 0; c < CDIM; ++c) v[c] = 0.f;
  for (int p = 0; p < NPART; ++p) {
    const float* row = &s_part[((size_t)p * B + b) * CO + o];
#pragma unroll
    for (int c = 0; c < CDIM; ++c) v[c] += row[c * 16];
  }
  float ns = 0.f;
#pragma unroll
  for (int c = 0; c < CDIM; ++c) ns += v[c] * v[c];
  float f = (ns / (1.f + ns)) / (sqrtf(ns) + 1e-10f);
#pragma unroll
  for (int c = 0; c < CDIM; ++c) out[(size_t)b * CO + c * 16 + o] = v[c] * f;
}

// ---------------------------------------------------------------------------
// Kernel 5: agreement via y-GEMM + W-contraction + atomic logits (round-3 ver).
// ---------------------------------------------------------------------------
__global__ void __launch_bounds__(256) k_agr(const float* __restrict__ W,
                                             const float* __restrict__ xt,
                                             const float* __restrict__ out,
                                             float* __restrict__ logits) {
  const int i0 = blockIdx.x * IT;
  const int b0 = blockIdx.y * BCH;
  const int t = threadIdx.x;
  const int rg = t >> 5;
  const int cg = t & 31;

  __shared__ __align__(16) float xtl[BCH][68];
  __shared__ __align__(16) float otile[BCH][161];

#pragma unroll
  for (int v = 0; v < 4; ++v) {
    int idx = v * 256 + t;
    int r = idx >> 4;
    int bq = idx & 15;
    int ii = r >> 3, k = r & 7;
    float4 xv = *reinterpret_cast<const float4*>(
        &xt[((size_t)(i0 + ii) * KDIM + k) * B + b0 + bq * 4]);
    xtl[bq * 4 + 0][r] = xv.x;
    xtl[bq * 4 + 1][r] = xv.y;
    xtl[bq * 4 + 2][r] = xv.z;
    xtl[bq * 4 + 3][r] = xv.w;
  }
#pragma unroll
  for (int v = 0; v < 10; ++v) {
    int idx = (v * 256 + t) * 4;
    int bb = idx / 160;
    int e = idx % 160;
    float4 ov = *reinterpret_cast<const float4*>(&out[(size_t)(b0 + bb) * CO + e]);
    otile[bb][e + 0] = ov.x;
    otile[bb][e + 1] = ov.y;
    otile[bb][e + 2] = ov.z;
    otile[bb][e + 3] = ov.w;
  }
  __syncthreads();

  float acc[8][5];
#pragma unroll
  for (int r = 0; r < 8; ++r)
#pragma unroll
    for (int j = 0; j < 5; ++j) acc[r][j] = 0.f;

  for (int b = 0; b < BCH; ++b) {
    float4 xa = *reinterpret_cast<const float4*>(&xtl[b][rg * 8]);
    float4 xb = *reinterpret_cast<const float4*>(&xtl[b][rg * 8 + 4]);
    float ov[5];
#pragma unroll
    for (int j = 0; j < 5; ++j) ov[j] = otile[b][cg * 5 + j];
    float xr[8] = {xa.x, xa.y, xa.z, xa.w, xb.x, xb.y, xb.z, xb.w};
#pragma unroll
    for (int r = 0; r < 8; ++r)
#pragma unroll
      for (int j = 0; j < 5; ++j) acc[r][j] += xr[r] * ov[j];
  }

  __syncthreads();
#pragma unroll
  for (int r = 0; r < 8; ++r)
#pragma unroll
    for (int j = 0; j < 5; ++j) otile[rg * 8 + r][cg * 5 + j] = acc[r][j];
  __syncthreads();

  if (t < 160) {
    int ii = t / 20, rem = t % 20, c = rem >> 1, oh = rem & 1;
    const float* Wp = &W[((size_t)(i0 + ii) * CDIM + c) * 128 + oh * 64];
    float sum = 0.f;
#pragma unroll
    for (int o = 0; o < 8; ++o) {
      float4 w0 = *reinterpret_cast<const float4*>(&Wp[o * 8]);
      float4 w1 = *reinterpret_cast<const float4*>(&Wp[o * 8 + 4]);
      int co = c * 16 + oh * 8 + o;
      sum += w0.x * otile[ii * 8 + 0][co] + w0.y * otile[ii * 8 + 1][co]
           + w0.z * otile[ii * 8 + 2][co] + w0.w * otile[ii * 8 + 3][co]
           + w1.x * otile[ii * 8 + 4][co] + w1.y * otile[ii * 8 + 5][co]
           + w1.z * otile[ii * 8 + 6][co] + w1.w * otile[ii * 8 + 7][co];
    }
    sum += __shfl_xor(sum, 1);
    if (oh == 0) atomicAdd(&logits[(i0 + ii) * CDIM + c], sum * (1.f / B));
  }
}

// ---------------------------------------------------------------------------
extern "C" void kernel_launch(void* const* d_in, const int* in_sizes, int n_in,
                              void* d_out, int out_size, void* d_ws, size_t ws_size,
                              hipStream_t stream) {
  const float* x = (const float*)d_in[0];
  const float* W = (const float*)d_in[1];
  float* out = (float*)d_out;

  float* xt     = (float*)d_ws;                       // I*K*B f32
  float* logits = xt + (size_t)IDIM * KDIM * B;       // I*C
  float* qT     = logits + IDIM * CDIM;               // C*I
  float* s_part = qT + IDIM * CDIM;                   // NPART*B*CO
  unsigned short* xtbT = (unsigned short*)(s_part + (size_t)NPART * B * CO); // B*IK bf16
  unsigned short* Wrb  = xtbT + (size_t)B * IK;       // CO*IK bf16

  k_transpose<<<dim3(IDIM / 32, B / 32, KDIM), dim3(32, 8), 0, stream>>>(x, xt, logits);
  k_xtb<<<dim3(IDIM / 128, B), 128, 0, stream>>>(x, xtbT);
  k_wr<<<dim3(IDIM / 128, CO), 128, 0, stream>>>(W, Wrb);

  for (int it = 0; it < 3; ++it) {
    k_q<<<CDIM, 256, 0, stream>>>(logits, qT);
    k_s<<<dim3(CDIM, 4, 8), 256, 0, stream>>>(qT, Wrb, xtbT, s_part);
    k_squash<<<16, 256, 0, stream>>>(s_part, out);
    if (it < 2) k_agr<<<dim3(IDIM / IT, BSPL), 256, 0, stream>>>(W, xt, out, logits);
  }
}

// Round 5
// 119.528 us; speedup vs baseline: 3.8367x; 1.0076x over previous
//
#include <hip/hip_runtime.h>

#define B 256
#define KDIM 8
#define IDIM 1152
#define CDIM 10
#define ODIM 16
#define CO 160
#define IK 9216        // IDIM*KDIM
#define NPART 8        // s_part splits
#define IT 8           // i's per k_agr block
#define BSPL 4         // b splits in k_agr
#define BCH (B / BSPL)

typedef __bf16 bf16x8 __attribute__((ext_vector_type(8)));
typedef unsigned short ushort8 __attribute__((ext_vector_type(8)));
typedef float f32x4 __attribute__((ext_vector_type(4)));

__device__ __forceinline__ unsigned short f2bf(float f) {
  unsigned u = __float_as_uint(f);
  unsigned r = u + 0x7fff + ((u >> 16) & 1);   // RNE
  return (unsigned short)(r >> 16);
}

union U8B8 { ushort8 u; bf16x8 h; };

// ---------------------------------------------------------------------------
// Kernel 1 (FUSED prep): role A (blocks 0..287): transpose x->xt f32 AND pack
// xtbT bf16 from one x read. role B (288..359): pack Wrb bf16; first 45 also
// zero logits.
// ---------------------------------------------------------------------------
__global__ void __launch_bounds__(256) k_prep(const float* __restrict__ x,
                                              const float* __restrict__ W,
                                              float* __restrict__ xt,
                                              unsigned short* __restrict__ xtbT,
                                              unsigned short* __restrict__ Wrb,
                                              float* __restrict__ logits) {
  const int bid = blockIdx.x;
  const int t = threadIdx.x;
  if (bid < 288) {
    const int i0 = (bid % 36) * 32;
    const int b0 = (bid / 36) * 32;
    __shared__ float tile[KDIM][32][33];       // [k][b][i] pad 33: conflict-free
    const int tx = t & 31, ty = t >> 5;        // tx: i on load / b on store
#pragma unroll
    for (int r = 0; r < 4; ++r) {
      int b = b0 + ty + r * 8;
#pragma unroll
      for (int k = 0; k < 8; ++k)
        tile[k][ty + r * 8][tx] = x[((size_t)b * KDIM + k) * IDIM + i0 + tx];
    }
    __syncthreads();
    // xt[i][k][b], lanes = consecutive b
#pragma unroll
    for (int r = 0; r < 4; ++r) {
      int iRow = ty + r * 8;
#pragma unroll
      for (int k = 0; k < 8; ++k)
        xt[((size_t)(i0 + iRow) * KDIM + k) * B + b0 + tx] = tile[k][tx][iRow];
    }
    // xtbT[b][i*8+k] ushort8, lanes = consecutive i
#pragma unroll
    for (int r = 0; r < 4; ++r) {
      int idx = r * 256 + t;
      int bb = idx >> 5;
      int ii = idx & 31;
      ushort8 v;
#pragma unroll
      for (int k = 0; k < 8; ++k) v[k] = f2bf(tile[k][bb][ii]);
      *reinterpret_cast<ushort8*>(&xtbT[(size_t)(b0 + bb) * IK + (size_t)(i0 + ii) * 8]) = v;
    }
  } else {
    const int bz = bid - 288;                  // 0..71
    const int i0 = bz * 16;
    const int ii = t & 15, rsub = t >> 4;      // lanes: consecutive i -> coalesced stores
#pragma unroll
    for (int pass = 0; pass < 10; ++pass) {
      int row = pass * 16 + rsub;              // c*16+o
      int c = row >> 4, o = row & 15;
      const float* src = &W[(((size_t)(i0 + ii) * CDIM + c) * ODIM + o) * KDIM];
      float4 w0 = *reinterpret_cast<const float4*>(src);
      float4 w1 = *reinterpret_cast<const float4*>(src + 4);
      ushort8 v;
      v[0] = f2bf(w0.x); v[1] = f2bf(w0.y); v[2] = f2bf(w0.z); v[3] = f2bf(w0.w);
      v[4] = f2bf(w1.x); v[5] = f2bf(w1.y); v[6] = f2bf(w1.z); v[7] = f2bf(w1.w);
      *reinterpret_cast<ushort8*>(&Wrb[(size_t)row * IK + (size_t)(i0 + ii) * 8]) = v;
    }
    if (bz < 45) logits[bz * 256 + t] = 0.f;
  }
}

// ---------------------------------------------------------------------------
// Kernel 2 (MFMA s-GEMM + FUSED per-class softmax).
// s[o,b] = sum_ik (q[c,i]*Wrb[c*16+o][ik]) * xtbT[b][ik]
// grid (10 c, 4 bt4, 8 g), block 256 = 4 waves; wave split s = g*4+w, 9 chunks.
// ---------------------------------------------------------------------------
__global__ void __launch_bounds__(256) k_s(const float* __restrict__ logits,
                                           const unsigned short* __restrict__ Wrb,
                                           const unsigned short* __restrict__ xtbT,
                                           float* __restrict__ s_part) {
  const int c = blockIdx.x, bt4 = blockIdx.y, g = blockIdx.z;
  const int t = threadIdx.x, w = t >> 6, l = t & 63;
  const int lr = l & 15, lq = l >> 4;
  const int s = g * 4 + w;

  __shared__ float cls[IDIM];
  __shared__ float red4[4];
  __shared__ float red[3 * 1088];

  // ---- softmax over i for class c (redundant per block; tiny) ----
  float m = -1e30f;
  for (int i = t; i < IDIM; i += 256) {
    float v = logits[i * CDIM + c];
    cls[i] = v;
    m = fmaxf(m, v);
  }
#pragma unroll
  for (int off = 32; off; off >>= 1) m = fmaxf(m, __shfl_xor(m, off));
  if ((t & 63) == 0) red4[t >> 6] = m;
  __syncthreads();
  m = fmaxf(fmaxf(red4[0], red4[1]), fmaxf(red4[2], red4[3]));
  __syncthreads();
  float ps = 0.f;
  for (int i = t; i < IDIM; i += 256) {
    float e = expf(cls[i] - m);
    cls[i] = e;
    ps += e;
  }
#pragma unroll
  for (int off = 32; off; off >>= 1) ps += __shfl_xor(ps, off);
  if ((t & 63) == 0) red4[t >> 6] = ps;
  __syncthreads();
  const float rinv = 1.f / (red4[0] + red4[1] + red4[2] + red4[3]);
  for (int i = t; i < IDIM; i += 256) cls[i] *= rinv;
  __syncthreads();

  // ---- MFMA main loop ----
  f32x4 acc[4];
#pragma unroll
  for (int j = 0; j < 4; ++j) acc[j] = (f32x4){0.f, 0.f, 0.f, 0.f};

  const unsigned short* Ap  = &Wrb[((size_t)c * 16 + lr) * IK + lq * 8];
  const unsigned short* Bp0 = &xtbT[((size_t)(bt4 * 64 +  0 + lr)) * IK + lq * 8];
  const unsigned short* Bp1 = &xtbT[((size_t)(bt4 * 64 + 16 + lr)) * IK + lq * 8];
  const unsigned short* Bp2 = &xtbT[((size_t)(bt4 * 64 + 32 + lr)) * IK + lq * 8];
  const unsigned short* Bp3 = &xtbT[((size_t)(bt4 * 64 + 48 + lr)) * IK + lq * 8];

#pragma unroll 3
  for (int t9 = 0; t9 < 9; ++t9) {
    const int kc = s * 9 + t9;
    const int off = kc * 32;
    ushort8 av = *reinterpret_cast<const ushort8*>(Ap + off);
    float qv = cls[kc * 4 + lq];
    U8B8 b0; b0.u = *reinterpret_cast<const ushort8*>(Bp0 + off);
    U8B8 b1; b1.u = *reinterpret_cast<const ushort8*>(Bp1 + off);
    U8B8 b2; b2.u = *reinterpret_cast<const ushort8*>(Bp2 + off);
    U8B8 b3; b3.u = *reinterpret_cast<const ushort8*>(Bp3 + off);
    U8B8 a;
#pragma unroll
    for (int e = 0; e < 8; ++e) {
      float f = __uint_as_float((unsigned)av[e] << 16) * qv;
      a.u[e] = f2bf(f);
    }
    acc[0] = __builtin_amdgcn_mfma_f32_16x16x32_bf16(a.h, b0.h, acc[0], 0, 0, 0);
    acc[1] = __builtin_amdgcn_mfma_f32_16x16x32_bf16(a.h, b1.h, acc[1], 0, 0, 0);
    acc[2] = __builtin_amdgcn_mfma_f32_16x16x32_bf16(a.h, b2.h, acc[2], 0, 0, 0);
    acc[3] = __builtin_amdgcn_mfma_f32_16x16x32_bf16(a.h, b3.h, acc[3], 0, 0, 0);
  }

  // ---- cross-wave reduce, store by wave 0 ----
  if (w) {
#pragma unroll
    for (int j = 0; j < 4; ++j)
#pragma unroll
      for (int j2 = 0; j2 < 4; ++j2)
        red[(w - 1) * 1088 + l * 17 + j * 4 + j2] = acc[j][j2];
  }
  __syncthreads();
  if (w == 0) {
#pragma unroll
    for (int r = 0; r < 3; ++r)
#pragma unroll
      for (int j = 0; j < 4; ++j)
#pragma unroll
        for (int j2 = 0; j2 < 4; ++j2)
          acc[j][j2] += red[r * 1088 + l * 17 + j * 4 + j2];
#pragma unroll
    for (int j = 0; j < 4; ++j)
#pragma unroll
      for (int j2 = 0; j2 < 4; ++j2)
        s_part[((size_t)g * B + bt4 * 64 + j * 16 + lr) * CO + c * 16 + lq * 4 + j2] =
            acc[j][j2];
  }
}

// ---------------------------------------------------------------------------
// Kernel 3 (FUSED squash+agreement, iters 0 and 1): each block squashes its
// own 64-b slice from s_part (fp32, identical math to k_squash), then y-GEMM
// + W-contraction + atomic logit update.
// ---------------------------------------------------------------------------
__global__ void __launch_bounds__(256) k_agr_sq(const float* __restrict__ W,
                                                const float* __restrict__ xt,
                                                const float* __restrict__ s_part,
                                                float* __restrict__ logits) {
  const int i0 = blockIdx.x * IT;
  const int b0 = blockIdx.y * BCH;
  const int t = threadIdx.x;
  const int rg = t >> 5;
  const int cg = t & 31;

  __shared__ __align__(16) float xtl[BCH][68];
  __shared__ __align__(16) float otile[BCH][161];

  // stage xt rows (64 rows x 64 b), transposed into [b][row]
#pragma unroll
  for (int v = 0; v < 4; ++v) {
    int idx = v * 256 + t;
    int r = idx >> 4;
    int bq = idx & 15;
    int ii = r >> 3, k = r & 7;
    float4 xv = *reinterpret_cast<const float4*>(
        &xt[((size_t)(i0 + ii) * KDIM + k) * B + b0 + bq * 4]);
    xtl[bq * 4 + 0][r] = xv.x;
    xtl[bq * 4 + 1][r] = xv.y;
    xtl[bq * 4 + 2][r] = xv.z;
    xtl[bq * 4 + 3][r] = xv.w;
  }

  // squash phase: otile[bb][c*16+o] = squash(sum_p s_part[p][b0+bb][c*16+o])
#pragma unroll
  for (int r = 0; r < 4; ++r) {
    int idx = r * 256 + t;       // 1024 = 64 bb x 16 o
    int bb = idx >> 4, o = idx & 15;
    float v[CDIM];
    float ns = 0.f;
#pragma unroll
    for (int cc = 0; cc < CDIM; ++cc) {
      float sv = 0.f;
#pragma unroll
      for (int p = 0; p < NPART; ++p)
        sv += s_part[((size_t)p * B + b0 + bb) * CO + cc * 16 + o];
      v[cc] = sv;
      ns += sv * sv;
    }
    float f = (ns / (1.f + ns)) / (sqrtf(ns) + 1e-10f);
#pragma unroll
    for (int cc = 0; cc < CDIM; ++cc) otile[bb][cc * 16 + o] = v[cc] * f;
  }
  __syncthreads();

  // y-GEMM: acc[r][j] over this b-chunk
  float acc[8][5];
#pragma unroll
  for (int r = 0; r < 8; ++r)
#pragma unroll
    for (int j = 0; j < 5; ++j) acc[r][j] = 0.f;

  for (int b = 0; b < BCH; ++b) {
    float4 xa = *reinterpret_cast<const float4*>(&xtl[b][rg * 8]);
    float4 xb = *reinterpret_cast<const float4*>(&xtl[b][rg * 8 + 4]);
    float ov[5];
#pragma unroll
    for (int j = 0; j < 5; ++j) ov[j] = otile[b][cg * 5 + j];
    float xr[8] = {xa.x, xa.y, xa.z, xa.w, xb.x, xb.y, xb.z, xb.w};
#pragma unroll
    for (int r = 0; r < 8; ++r)
#pragma unroll
      for (int j = 0; j < 5; ++j) acc[r][j] += xr[r] * ov[j];
  }

  __syncthreads();
#pragma unroll
  for (int r = 0; r < 8; ++r)
#pragma unroll
    for (int j = 0; j < 5; ++j) otile[rg * 8 + r][cg * 5 + j] = acc[r][j];
  __syncthreads();

  if (t < 160) {
    int ii = t / 20, rem = t % 20, c = rem >> 1, oh = rem & 1;
    const float* Wp = &W[((size_t)(i0 + ii) * CDIM + c) * 128 + oh * 64];
    float sum = 0.f;
#pragma unroll
    for (int o = 0; o < 8; ++o) {
      float4 w0 = *reinterpret_cast<const float4*>(&Wp[o * 8]);
      float4 w1 = *reinterpret_cast<const float4*>(&Wp[o * 8 + 4]);
      int co = c * 16 + oh * 8 + o;
      sum += w0.x * otile[ii * 8 + 0][co] + w0.y * otile[ii * 8 + 1][co]
           + w0.z * otile[ii * 8 + 2][co] + w0.w * otile[ii * 8 + 3][co]
           + w1.x * otile[ii * 8 + 4][co] + w1.y * otile[ii * 8 + 5][co]
           + w1.z * otile[ii * 8 + 6][co] + w1.w * otile[ii * 8 + 7][co];
    }
    sum += __shfl_xor(sum, 1);
    if (oh == 0) atomicAdd(&logits[(i0 + ii) * CDIM + c], sum * (1.f / B));
  }
}

// ---------------------------------------------------------------------------
// Kernel 4: final reduce + squash -> d_out (last iteration only).
// ---------------------------------------------------------------------------
__global__ void __launch_bounds__(256) k_squash(const float* __restrict__ s_part,
                                                float* __restrict__ out) {
  int idx = blockIdx.x * 256 + threadIdx.x;
  int b = idx >> 4, o = idx & 15;
  float v[CDIM];
#pragma unroll
  for (int c = 0; c < CDIM; ++c) v[c] = 0.f;
  for (int p = 0; p < NPART; ++p) {
    const float* row = &s_part[((size_t)p * B + b) * CO + o];
#pragma unroll
    for (int c = 0; c < CDIM; ++c) v[c] += row[c * 16];
  }
  float ns = 0.f;
#pragma unroll
  for (int c = 0; c < CDIM; ++c) ns += v[c] * v[c];
  float f = (ns / (1.f + ns)) / (sqrtf(ns) + 1e-10f);
#pragma unroll
  for (int c = 0; c < CDIM; ++c) out[(size_t)b * CO + c * 16 + o] = v[c] * f;
}

// ---------------------------------------------------------------------------
extern "C" void kernel_launch(void* const* d_in, const int* in_sizes, int n_in,
                              void* d_out, int out_size, void* d_ws, size_t ws_size,
                              hipStream_t stream) {
  const float* x = (const float*)d_in[0];
  const float* W = (const float*)d_in[1];
  float* out = (float*)d_out;

  float* xt     = (float*)d_ws;                       // I*K*B f32
  float* logits = xt + (size_t)IDIM * KDIM * B;       // I*C
  float* s_part = logits + IDIM * CDIM;               // NPART*B*CO
  unsigned short* xtbT = (unsigned short*)(s_part + (size_t)NPART * B * CO); // B*IK
  unsigned short* Wrb  = xtbT + (size_t)B * IK;       // CO*IK

  k_prep<<<360, 256, 0, stream>>>(x, W, xt, xtbT, Wrb, logits);

  for (int it = 0; it < 3; ++it) {
    k_s<<<dim3(CDIM, 4, NPART), 256, 0, stream>>>(logits, Wrb, xtbT, s_part);
    if (it < 2)
      k_agr_sq<<<dim3(IDIM / IT, BSPL), 256, 0, stream>>>(W, xt, s_part, logits);
    else
      k_squash<<<16, 256, 0, stream>>>(s_part, out);
  }
}